// Round 1
// baseline (659.673 us; speedup 1.0000x reference)
//
#include <hip/hip_runtime.h>

#define HOPS   3
#define LABELS 10
#define DIM    128

// ---------------------------------------------------------------------------
// Kernel 1: block-strided segmented reduction.
// Block = 192 threads = 3 waves; wave h handles hop h; lane owns dims
// [2*lane, 2*lane+1]. Per-thread register accumulators acc[10] (float2).
// labels[n] is uniform across the block per iteration -> readfirstlane makes
// the 10-way label dispatch a scalar branch chain (s_cmp/s_cbranch), so the
// hot loop is ~1 coalesced dwordx2 load + 3 VALU adds per node per wave.
// ---------------------------------------------------------------------------
__global__ __launch_bounds__(192) void mhce_reduce(
    const float* __restrict__ emb,      // [HOPS][N][DIM]
    const int*   __restrict__ labels,   // [N]
    float*       __restrict__ ws_sums,  // [HOPS][LABELS][DIM]
    float*       __restrict__ ws_counts,// [LABELS]
    int N)
{
    const int tid  = threadIdx.x;
    const int h    = tid >> 6;   // 0..2 (hop, one wave each)
    const int lane = tid & 63;   // 0..63
    const int d0   = lane << 1;  // dim pair

    float2 acc[LABELS];
#pragma unroll
    for (int l = 0; l < LABELS; ++l) acc[l] = make_float2(0.f, 0.f);
    float cnt[LABELS];
#pragma unroll
    for (int l = 0; l < LABELS; ++l) cnt[l] = 0.f;

    const float* hop_base = emb + (size_t)h * N * DIM + d0;

    for (int n = blockIdx.x; n < N; n += gridDim.x) {
        const int lab = __builtin_amdgcn_readfirstlane(labels[n]);
        const float2 v =
            *reinterpret_cast<const float2*>(hop_base + (size_t)n * DIM);
#pragma unroll
        for (int l = 0; l < LABELS; ++l) {
            if (lab == l) {          // uniform scalar branch after readfirstlane
                acc[l].x += v.x;
                acc[l].y += v.y;
                cnt[l]   += 1.0f;    // every thread counts identically
            }
        }
    }

    // Fold per-thread partials into global workspace. Each thread owns a
    // distinct (h, dim-pair) slice, so lanes hit distinct contiguous addrs;
    // contention is only across the 2048 blocks (~2048 serialized adds/addr).
    float* out_base = ws_sums + (size_t)h * LABELS * DIM + d0;
#pragma unroll
    for (int l = 0; l < LABELS; ++l) {
        atomicAdd(out_base + l * DIM + 0, acc[l].x);
        atomicAdd(out_base + l * DIM + 1, acc[l].y);
    }
    if (tid == 0) {
#pragma unroll
        for (int l = 0; l < LABELS; ++l) atomicAdd(&ws_counts[l], cnt[l]);
    }
}

// ---------------------------------------------------------------------------
// Kernel 2: finalize — centers = sums / max(cnt,1) + weight; append counts.
// ---------------------------------------------------------------------------
__global__ __launch_bounds__(256) void mhce_finalize(
    const float* __restrict__ ws_sums,
    const float* __restrict__ ws_counts,
    const float* __restrict__ weight,   // [HOPS][LABELS][DIM]
    float*       __restrict__ out)      // [HOPS*LABELS*DIM + LABELS]
{
    const int i = blockIdx.x * blockDim.x + threadIdx.x;
    if (i < HOPS * LABELS * DIM) {
        const int l = (i / DIM) % LABELS;
        const float c    = ws_counts[l];
        const float safe = fmaxf(c, 1.0f);
        out[i] = ws_sums[i] / safe + weight[i];
    }
    if (i < LABELS) {
        out[HOPS * LABELS * DIM + i] = ws_counts[i];
    }
}

extern "C" void kernel_launch(void* const* d_in, const int* in_sizes, int n_in,
                              void* d_out, int out_size, void* d_ws, size_t ws_size,
                              hipStream_t stream)
{
    const float* emb    = (const float*)d_in[0];   // [3][N][128] fp32
    const int*   labels = (const int*)  d_in[1];   // [N] int
    const float* weight = (const float*)d_in[2];   // [3][10][128] fp32
    float*       out    = (float*)d_out;           // 3*10*128 + 10 fp32

    const int N = in_sizes[1];

    float* ws_sums   = (float*)d_ws;                       // 3840 floats
    float* ws_counts = ws_sums + HOPS * LABELS * DIM;      // 10 floats

    // Workspace is re-poisoned to 0xAA before every timed launch — zero it.
    hipMemsetAsync(d_ws, 0,
                   (HOPS * LABELS * DIM + LABELS) * sizeof(float), stream);

    int grid = 2048;
    if (grid > N) grid = N;
    mhce_reduce<<<grid, 192, 0, stream>>>(emb, labels, ws_sums, ws_counts, N);

    const int total = HOPS * LABELS * DIM;
    mhce_finalize<<<(total + 255) / 256, 256, 0, stream>>>(
        ws_sums, ws_counts, weight, out);
}